// Round 3
// baseline (139.139 us; speedup 1.0000x reference)
//
#include <hip/hip_runtime.h>
#include <stdint.h>

#define B_  4096
#define F_  512
#define T_  2048
#define D_  4
#define M_  (T_ * D_)   // 8192 GEMM-M (trees*dims)
#define KC_ (F_ / 8)    // 64 16-byte k-chunks per row
#define TAU 0.2018004745467103f

typedef __attribute__((ext_vector_type(8)))  short bf16x8;
typedef __attribute__((ext_vector_type(16))) float f32x16;

static __device__ __forceinline__ unsigned short f2bf(float f) {
  union { float f; uint32_t u; } v; v.f = f;
  uint32_t r = v.u + 0x7fffu + ((v.u >> 16) & 1u);  // RNE
  return (unsigned short)(r >> 16);
}

// ---------------------------------------------------------------------------
// Prep (unchanged, verified): x -> xbF frag-major bf16, softmax(logits) -> wbF
// frag-major. Cell (kc, n) = 16B of 8 consecutive k for row n.
// ---------------------------------------------------------------------------
__global__ __launch_bounds__(256) void prep(
    const float* __restrict__ x, const float* __restrict__ logits,
    unsigned short* __restrict__ xbF, unsigned short* __restrict__ wbF) {
  if (blockIdx.x < 1024) {
    int w = blockIdx.x * 4 + (threadIdx.x >> 6);
    int l = threadIdx.x & 63;
    int n  = ((w & 511) << 3) + (l >> 3);
    int kc = ((w >> 9) << 3) + (l & 7);
    const float4* p = (const float4*)(x + (size_t)n * F_ + kc * 8);
    float4 a = p[0], b = p[1];
    bf16x8 o;
    o[0] = (short)f2bf(a.x); o[1] = (short)f2bf(a.y);
    o[2] = (short)f2bf(a.z); o[3] = (short)f2bf(a.w);
    o[4] = (short)f2bf(b.x); o[5] = (short)f2bf(b.y);
    o[6] = (short)f2bf(b.z); o[7] = (short)f2bf(b.w);
    *(bf16x8*)(xbF + ((size_t)kc * B_ + n) * 8) = o;
  } else {
    __shared__ uint32_t ls[4 * 257];
    int bj = blockIdx.x - 1024;
    int wv = threadIdx.x >> 6, l = threadIdx.x & 63;
    int m  = bj * 4 + wv;
    const float* src = logits + (size_t)m * F_ + l * 8;
    float4 v0 = *(const float4*)src;
    float4 v1 = *(const float4*)(src + 4);
    float mx = fmaxf(fmaxf(fmaxf(v0.x, v0.y), fmaxf(v0.z, v0.w)),
                     fmaxf(fmaxf(v1.x, v1.y), fmaxf(v1.z, v1.w)));
    #pragma unroll
    for (int s = 32; s >= 1; s >>= 1) mx = fmaxf(mx, __shfl_xor(mx, s, 64));
    float e[8];
    e[0] = __expf(v0.x - mx); e[1] = __expf(v0.y - mx);
    e[2] = __expf(v0.z - mx); e[3] = __expf(v0.w - mx);
    e[4] = __expf(v1.x - mx); e[5] = __expf(v1.y - mx);
    e[6] = __expf(v1.z - mx); e[7] = __expf(v1.w - mx);
    float sm = e[0] + e[1] + e[2] + e[3] + e[4] + e[5] + e[6] + e[7];
    #pragma unroll
    for (int s = 32; s >= 1; s >>= 1) sm += __shfl_xor(sm, s, 64);
    float inv = 1.0f / sm;
    union { bf16x8 v; uint32_t u[4]; } cv;
    #pragma unroll
    for (int i = 0; i < 8; i++) cv.v[i] = (short)f2bf(e[i] * inv);
    #pragma unroll
    for (int j = 0; j < 4; j++) ls[wv * 257 + l * 4 + j] = cv.u[j];
    __syncthreads();
    int kc = threadIdx.x >> 2, mm = threadIdx.x & 3;
    union { uint32_t u[4]; bf16x8 v; } rv;
    #pragma unroll
    for (int j = 0; j < 4; j++) rv.u[j] = ls[mm * 257 + kc * 4 + j];
    *(bf16x8*)(wbF + ((size_t)kc * M_ + bj * 4 + mm) * 8) = rv.v;
  }
}

// ---------------------------------------------------------------------------
// LDS-ratio-first GEMM: 256x256 block, 4 waves (2x2), wave tile 128x128.
// Rationale (round-2 post-mortem): all prior variants used 128x64 wave tiles
// = 0.75 ds_read_b128 per MFMA -> LDS pipe (~20us/CU) ~ MFMA pipe (13.8us),
// and barrier-lockstep serialized them -> 50us at 27% MfmaUtil regardless of
// schedule. 128x128 wave tile = 0.5 reads/MFMA -> LDS reads ~10us < MFMA
// floor; acc[4][4] f32x16 = 256 regs -> 1 wave/SIMD (~420 regs total,
// launch_bounds(256,1)); overlap now comes from within-wave ILP: per BK=64
// tile, 32 b128 reads stream against 64 MFMAs via compiler's counted lgkmcnt
// (near-optimal per m97 asm evidence).
// Double-buffered LDS 2x64KB = 128KB; prefetch distance = 1 full tile, so the
// __syncthreads() vmcnt-drain at tile end waits on loads issued ~2000 cycles
// earlier (HBM ~900) -> drain is free; plain __syncthreads() is exactly the
// needed semantic (no raw-asm barriers required).
// Frag-major [kc][256 row] 16B cells: conflict-free b128 reads + linear 1KB
// global_load_lds chunks (rule #21 satisfied with no swizzle).
// Grid 32x16 = 512 blocks = 2 rounds of 1 block/CU.
// ---------------------------------------------------------------------------
__global__ __launch_bounds__(256, 1) void odst_mfma(
    const unsigned short* __restrict__ wbF,  // frag-major [KC][M] 16B cells
    const unsigned short* __restrict__ xbF,  // frag-major [KC][B] 16B cells
    const float* __restrict__ thr,           // [T][4]
    const float* __restrict__ leaf,          // [T][16]
    float* __restrict__ out) {               // [B][T]
  __shared__ __align__(16) char smem[131072];

  const int tid  = threadIdx.x;
  const int lane = tid & 63, wid = tid >> 6;   // 4 waves
  const int wm = wid >> 1, wn = wid & 1;       // 2 (m) x 2 (n)
  const int col = lane & 31, hi = lane >> 5;
  const int m0 = blockIdx.x * 256;
  const int n0 = blockIdx.y * 256;

  // wave `wid` stages kc slots {2*wid, 2*wid+1} of each BK=64 tile
  const unsigned short* gA = wbF + ((size_t)(2 * wid) * M_ + m0 + lane) * 8;
  const unsigned short* gB = xbF + ((size_t)(2 * wid) * B_ + n0 + lane) * 8;

  f32x16 acc[4][4] = {};

  // Stage one full tile (A 32KB + B 32KB) into buf[t&1]: 16 loads/wave.
  auto stage = [&](int t) {
    char* base = smem + (t & 1) * 65536;
    #pragma unroll
    for (int j = 0; j < 8; ++j) {
      int kc = j >> 2;            // local kc slot within this wave's pair
      int r  = (j & 3) * 64;      // 64-row chunk
      __builtin_amdgcn_global_load_lds(
          (const __attribute__((address_space(1))) uint32_t*)(
              gA + ((size_t)(t * 8 + kc) * M_ + r) * 8),
          (__attribute__((address_space(3))) uint32_t*)(
              base + ((2 * wid + kc) * 256 + r) * 16),
          16, 0, 0);
      __builtin_amdgcn_global_load_lds(
          (const __attribute__((address_space(1))) uint32_t*)(
              gB + ((size_t)(t * 8 + kc) * B_ + r) * 8),
          (__attribute__((address_space(3))) uint32_t*)(
              base + 32768 + ((2 * wid + kc) * 256 + r) * 16),
          16, 0, 0);
    }
  };

  // Consume one tile: 4 K=16 slices; per slice 8 b128 reads + 16 MFMAs.
  auto compute = [&](int t) {
    const char* base = smem + (t & 1) * 65536;
    #pragma unroll
    for (int s = 0; s < 4; ++s) {
      bf16x8 a[4], b[4];
      #pragma unroll
      for (int f = 0; f < 4; ++f) {
        a[f] = *(const bf16x8*)(base +
            (((2 * s + hi) * 256) + wm * 128 + f * 32 + col) * 16);
        b[f] = *(const bf16x8*)(base + 32768 +
            (((2 * s + hi) * 256) + wn * 128 + f * 32 + col) * 16);
      }
      #pragma unroll
      for (int mf = 0; mf < 4; ++mf)
        #pragma unroll
        for (int nf = 0; nf < 4; ++nf)
          acc[mf][nf] = __builtin_amdgcn_mfma_f32_32x32x16_bf16(
              a[mf], b[nf], acc[mf][nf], 0, 0, 0);
    }
  };

  stage(0);
  __syncthreads();                 // vmcnt(0) drain: tile 0 resident

  #pragma unroll 2
  for (int t = 0; t < 8; ++t) {    // K = 8 tiles x BK=64
    if (t < 7) stage(t + 1);       // other buffer (tile t-1 reads done)
    compute(t);
    __syncthreads();               // drains stage(t+1) (issued ~2000cy ago)
  }

  // ---- fused epilogue: C-layout n=col, d=reg&3, tree-in-frag=2g+hi ----
  float* eb = (float*)smem;                  // [256 batch][66] floats
  const float inv_tau = 1.0f / TAU;
  const int t0 = m0 >> 2;                    // 64 trees per block
  #pragma unroll
  for (int mf = 0; mf < 4; ++mf) {
    #pragma unroll
    for (int g = 0; g < 4; ++g) {
      int tl = wm * 32 + mf * 8 + 2 * g + hi;
      int tg = t0 + tl;
      float4 th  = *(const float4*)(thr + tg * 4);
      float4 lf0 = *(const float4*)(leaf + tg * 16);
      float4 lf1 = *(const float4*)(leaf + tg * 16 + 4);
      float4 lf2 = *(const float4*)(leaf + tg * 16 + 8);
      float4 lf3 = *(const float4*)(leaf + tg * 16 + 12);
      float c2x = th.x * inv_tau, c2y = th.y * inv_tau,
            c2z = th.z * inv_tau, c2w = th.w * inv_tau;
      #pragma unroll
      for (int nf = 0; nf < 4; ++nf) {
        float p0 = __builtin_amdgcn_rcpf(1.0f + __expf(fmaf(acc[mf][nf][g * 4 + 0], -inv_tau, c2x)));
        float p1 = __builtin_amdgcn_rcpf(1.0f + __expf(fmaf(acc[mf][nf][g * 4 + 1], -inv_tau, c2y)));
        float p2 = __builtin_amdgcn_rcpf(1.0f + __expf(fmaf(acc[mf][nf][g * 4 + 2], -inv_tau, c2z)));
        float p3 = __builtin_amdgcn_rcpf(1.0f + __expf(fmaf(acc[mf][nf][g * 4 + 3], -inv_tau, c2w)));
        float q0 = 1.0f - p0, q1 = 1.0f - p1, q2 = 1.0f - p2, q3 = 1.0f - p3;
        float A0 = lf0.x * q0 + lf0.y * p0;
        float A1 = lf0.z * q0 + lf0.w * p0;
        float A2 = lf1.x * q0 + lf1.y * p0;
        float A3 = lf1.z * q0 + lf1.w * p0;
        float A4 = lf2.x * q0 + lf2.y * p0;
        float A5 = lf2.z * q0 + lf2.w * p0;
        float A6 = lf3.x * q0 + lf3.y * p0;
        float A7 = lf3.z * q0 + lf3.w * p0;
        float B0 = A0 * q1 + A1 * p1;
        float B1 = A2 * q1 + A3 * p1;
        float B2 = A4 * q1 + A5 * p1;
        float B3 = A6 * q1 + A7 * p1;
        float C0 = B0 * q2 + B1 * p2;
        float C1 = B2 * q2 + B3 * p2;
        float o  = C0 * q3 + C1 * p3;
        int bl = wn * 128 + nf * 32 + col;   // batch within block [0,256)
        eb[bl * 66 + tl] = o;                // stride 66: 2-way (free)
      }
    }
  }
  __syncthreads();

  // coalesced store: 256 batch rows x 64 trees; float2-pair LDS reads
  // (stride 66 words -> 8B alignment), float4 global stores.
  #pragma unroll
  for (int pass = 0; pass < 16; ++pass) {
    int row = pass * 16 + (tid >> 4);
    int s   = tid & 15;
    const float* p = eb + row * 66 + s * 4;
    float2 v0 = *(const float2*)p;
    float2 v1 = *(const float2*)(p + 2);
    float4 v;
    v.x = v0.x; v.y = v0.y; v.z = v1.x; v.w = v1.y;
    *(float4*)(out + (size_t)(n0 + row) * T_ + t0 + s * 4) = v;
  }
}

extern "C" void kernel_launch(void* const* d_in, const int* in_sizes, int n_in,
                              void* d_out, int out_size, void* d_ws, size_t ws_size,
                              hipStream_t stream) {
  const float* x    = (const float*)d_in[0];  // (B, F)
  const float* fl   = (const float*)d_in[1];  // (T, D, F)
  const float* thr  = (const float*)d_in[2];  // (T, D)
  const float* leaf = (const float*)d_in[3];  // (T, 16)
  float* out = (float*)d_out;                 // (B, T)

  unsigned short* wbF = (unsigned short*)d_ws;                                  // 8 MB
  unsigned short* xbF = (unsigned short*)((char*)d_ws + (size_t)KC_ * M_ * 16); // 4 MB

  prep<<<dim3(1024 + M_ / 4), dim3(256), 0, stream>>>(x, fl, xbF, wbF);
  odst_mfma<<<dim3(M_ / 256, B_ / 256), dim3(256), 0, stream>>>(wbF, xbF, thr, leaf, out);
}

// Round 4
// 128.258 us; speedup vs baseline: 1.0848x; 1.0848x over previous
//
#include <hip/hip_runtime.h>
#include <stdint.h>

#define B_  4096
#define F_  512
#define T_  2048
#define D_  4
#define M_  (T_ * D_)   // 8192 GEMM-M (trees*dims)
#define KC_ (F_ / 8)    // 64 16-byte k-chunks per row
#define TAU 0.2018004745467103f

typedef __attribute__((ext_vector_type(8)))  short bf16x8;
typedef __attribute__((ext_vector_type(16))) float f32x16;

static __device__ __forceinline__ unsigned short f2bf(float f) {
  union { float f; uint32_t u; } v; v.f = f;
  uint32_t r = v.u + 0x7fffu + ((v.u >> 16) & 1u);  // RNE
  return (unsigned short)(r >> 16);
}

// ---------------------------------------------------------------------------
// Prep (unchanged, verified): x -> xbF frag-major bf16, softmax(logits) -> wbF
// frag-major. Cell (kc, n) = 16B of 8 consecutive k for row n.
// ---------------------------------------------------------------------------
__global__ __launch_bounds__(256) void prep(
    const float* __restrict__ x, const float* __restrict__ logits,
    unsigned short* __restrict__ xbF, unsigned short* __restrict__ wbF) {
  if (blockIdx.x < 1024) {
    int w = blockIdx.x * 4 + (threadIdx.x >> 6);
    int l = threadIdx.x & 63;
    int n  = ((w & 511) << 3) + (l >> 3);
    int kc = ((w >> 9) << 3) + (l & 7);
    const float4* p = (const float4*)(x + (size_t)n * F_ + kc * 8);
    float4 a = p[0], b = p[1];
    bf16x8 o;
    o[0] = (short)f2bf(a.x); o[1] = (short)f2bf(a.y);
    o[2] = (short)f2bf(a.z); o[3] = (short)f2bf(a.w);
    o[4] = (short)f2bf(b.x); o[5] = (short)f2bf(b.y);
    o[6] = (short)f2bf(b.z); o[7] = (short)f2bf(b.w);
    *(bf16x8*)(xbF + ((size_t)kc * B_ + n) * 8) = o;
  } else {
    __shared__ uint32_t ls[4 * 257];
    int bj = blockIdx.x - 1024;
    int wv = threadIdx.x >> 6, l = threadIdx.x & 63;
    int m  = bj * 4 + wv;
    const float* src = logits + (size_t)m * F_ + l * 8;
    float4 v0 = *(const float4*)src;
    float4 v1 = *(const float4*)(src + 4);
    float mx = fmaxf(fmaxf(fmaxf(v0.x, v0.y), fmaxf(v0.z, v0.w)),
                     fmaxf(fmaxf(v1.x, v1.y), fmaxf(v1.z, v1.w)));
    #pragma unroll
    for (int s = 32; s >= 1; s >>= 1) mx = fmaxf(mx, __shfl_xor(mx, s, 64));
    float e[8];
    e[0] = __expf(v0.x - mx); e[1] = __expf(v0.y - mx);
    e[2] = __expf(v0.z - mx); e[3] = __expf(v0.w - mx);
    e[4] = __expf(v1.x - mx); e[5] = __expf(v1.y - mx);
    e[6] = __expf(v1.z - mx); e[7] = __expf(v1.w - mx);
    float sm = e[0] + e[1] + e[2] + e[3] + e[4] + e[5] + e[6] + e[7];
    #pragma unroll
    for (int s = 32; s >= 1; s >>= 1) sm += __shfl_xor(sm, s, 64);
    float inv = 1.0f / sm;
    union { bf16x8 v; uint32_t u[4]; } cv;
    #pragma unroll
    for (int i = 0; i < 8; i++) cv.v[i] = (short)f2bf(e[i] * inv);
    #pragma unroll
    for (int j = 0; j < 4; j++) ls[wv * 257 + l * 4 + j] = cv.u[j];
    __syncthreads();
    int kc = threadIdx.x >> 2, mm = threadIdx.x & 3;
    union { uint32_t u[4]; bf16x8 v; } rv;
    #pragma unroll
    for (int j = 0; j < 4; j++) rv.u[j] = ls[mm * 257 + kc * 4 + j];
    *(bf16x8*)(wbF + ((size_t)kc * M_ + bj * 4 + mm) * 8) = rv.v;
  }
}

// ---------------------------------------------------------------------------
// Round-4 change vs round-2 (single variable): XCD-chunked block swizzle.
// Mechanism (round-3 post-mortem): logical staged traffic is 384MB (A 8MB
// re-read x32 n-blocks, B 4MB x32 m-blocks); FETCH is only 24MB, so ~360MB
// is served by L2/L3. At 50us that is 7.7 TB/s = Infinity-Cache-class BW:
// default round-robin dispatch spreads neighboring m-blocks across XCDs, so
// each 4MB XCD-L2 thrashes and stages come from L3 -> the vmcnt waits all
// schedule variants failed to hide. Fix: bid%8 = XCD (round-robin dispatch),
// each XCD owns a contiguous 8m x 16y rectangle of the 32x32 grid, y-fast:
// active A strip 256KB (shared by 16 consecutive blocks) + resident B set
// 16x128KB = 2MB -> <=4MB, fits the XCD's private L2. Stage reads become
// L2 hits after first touch.
//
// GEMM structure is round-2's verified best (50us): 256x128 tile, 4 waves
// (2m x 2n), wave tile 128x64, BK=32 double-buffered, 48KB LDS ->
// 2 blocks/CU, counted vmcnt (never 0 in steady state), grid 1024 = 1 round.
// ---------------------------------------------------------------------------
#define SBAR()  do { __builtin_amdgcn_sched_barrier(0); \
                     __builtin_amdgcn_s_barrier(); \
                     __builtin_amdgcn_sched_barrier(0); } while (0)
#define LGKM0() do { asm volatile("s_waitcnt lgkmcnt(0)" ::: "memory"); \
                     __builtin_amdgcn_sched_barrier(0); } while (0)
#define VMCNT(n) do { asm volatile("s_waitcnt vmcnt(" #n ")" ::: "memory"); \
                      __builtin_amdgcn_sched_barrier(0); } while (0)

__global__ __launch_bounds__(256, 2) void odst_mfma(
    const unsigned short* __restrict__ wbF,  // frag-major [KC][M] 16B cells
    const unsigned short* __restrict__ xbF,  // frag-major [KC][B] 16B cells
    const float* __restrict__ thr,           // [T][4]
    const float* __restrict__ leaf,          // [T][16]
    float* __restrict__ out) {               // [B][T]
  __shared__ __align__(16) char smem[49152];

  const int tid  = threadIdx.x;
  const int lane = tid & 63, wid = tid >> 6;   // 4 waves
  const int wm = wid >> 1, wn = wid & 1;       // 2 (m) x 2 (n)
  const int col = lane & 31, hi = lane >> 5;

  // XCD-chunked swizzle: 1024 blocks, xcd = bid%8 owns an 8m x 16y rectangle
  // of the 32(m) x 32(y) grid; y-fast within the chunk (A-strip reuse).
  const int bid = blockIdx.x;
  const int k   = bid & 7, r = bid >> 3;       // r in [0,128)
  const int mb  = (k >> 1) * 8 + (r >> 4);     // [0,32)
  const int yb  = (k & 1) * 16 + (r & 15);     // [0,32)
  const int m0 = mb * 256;
  const int n0 = yb * 128;

  // wave `wid` stages kc slot `wid` of each tile (4 kc slots per BK=32 tile)
  const unsigned short* gA = wbF + ((size_t)wid * M_ + m0 + lane) * 8;
  const unsigned short* gB = xbF + ((size_t)wid * B_ + n0 + lane) * 8;

  auto stA = [&](int t, int j) {               // A rows [j*64, j*64+64)
    char* base = smem + (t & 1) * 24576;
    __builtin_amdgcn_global_load_lds(
        (const __attribute__((address_space(1))) uint32_t*)(
            gA + ((size_t)t * 4 * M_ + j * 64) * 8),
        (__attribute__((address_space(3))) uint32_t*)(
            base + (wid * 256 + j * 64) * 16),
        16, 0, 0);
  };
  auto stB = [&](int t, int j) {               // B rows [j*64, j*64+64)
    char* base = smem + (t & 1) * 24576 + 16384;
    __builtin_amdgcn_global_load_lds(
        (const __attribute__((address_space(1))) uint32_t*)(
            gB + ((size_t)t * 4 * B_ + j * 64) * 8),
        (__attribute__((address_space(3))) uint32_t*)(
            base + (wid * 128 + j * 64) * 16),
        16, 0, 0);
  };

  bf16x8 alo[2][2], ahi[2][2], b[2][2];
  f32x16 acc[4][2] = {};

  auto ldA = [&](bf16x8 (&a)[2][2], int t, int mh) {  // m-frags mh*2+{0,1}
    const char* base = smem + (t & 1) * 24576;
    #pragma unroll
    for (int ks = 0; ks < 2; ++ks)
      #pragma unroll
      for (int mf = 0; mf < 2; ++mf)
        a[mf][ks] = *(const bf16x8*)(base +
            ((2 * ks + hi) * 256 + wm * 128 + (mh * 2 + mf) * 32 + col) * 16);
  };
  auto ldB = [&](int t) {
    const char* base = smem + (t & 1) * 24576 + 16384;
    #pragma unroll
    for (int ks = 0; ks < 2; ++ks)
      #pragma unroll
      for (int nf = 0; nf < 2; ++nf)
        b[nf][ks] = *(const bf16x8*)(base +
            ((2 * ks + hi) * 128 + wn * 64 + nf * 32 + col) * 16);
  };
  auto mmah = [&](bf16x8 (&a)[2][2], int mh) {
    __builtin_amdgcn_s_setprio(1);
    #pragma unroll
    for (int ks = 0; ks < 2; ++ks)
      #pragma unroll
      for (int mf = 0; mf < 2; ++mf)
        #pragma unroll
        for (int nf = 0; nf < 2; ++nf)
          acc[mh * 2 + mf][nf] = __builtin_amdgcn_mfma_f32_32x32x16_bf16(
              a[mf][ks], b[nf][ks], acc[mh * 2 + mf][nf], 0, 0, 0);
    __builtin_amdgcn_s_setprio(0);
  };

  // ---- prologue: tile 0 full (6) + tile 1 partial {A j0,j2; B j0,j1} (4) ----
  stA(0, 0); stA(0, 1); stA(0, 2); stA(0, 3); stB(0, 0); stB(0, 1);
  stA(1, 0); stA(1, 2); stB(1, 0); stB(1, 1);
  VMCNT(4);                                  // tile 0's 6 loads landed
  SBAR();

  #pragma unroll
  for (int t = 0; t < 16; ++t) {             // K = 16 tiles x BK=32
    // -- q0: m-frags 0,1 --
    if (t < 15) { stA(t + 1, 1); stA(t + 1, 3); }   // pending buffer
    ldA(alo, t, 0);
    ldB(t);
    SBAR(); LGKM0();
    mmah(alo, 0);
    SBAR();
    // -- q1: m-frags 2,3 --
    if (t < 14) { stA(t + 2, 0); stA(t + 2, 2); stB(t + 2, 0); stB(t + 2, 1); }
    ldA(ahi, t, 1);
    if (t < 14) { VMCNT(4); }                // tile t+1 fully resident
    else if (t == 14) { VMCNT(0); }          // tail drain for tile 15
    SBAR(); LGKM0();
    mmah(ahi, 1);
    SBAR();
  }

  __syncthreads();  // all frag reads done; LDS reusable for epilogue

  // ---- fused epilogue: C-layout n=col, d=reg&3, tree-in-frag=2g+hi ----
  float* eb = (float*)smem;                  // [128 batch][68] floats
  const float inv_tau = 1.0f / TAU;
  const int t0 = m0 >> 2;                    // 64 trees per block
  #pragma unroll
  for (int af = 0; af < 4; ++af) {
    #pragma unroll
    for (int g = 0; g < 4; ++g) {
      int tl = wm * 32 + af * 8 + 2 * g + hi;
      int tg = t0 + tl;
      float4 th  = *(const float4*)(thr + tg * 4);
      float4 lf0 = *(const float4*)(leaf + tg * 16);
      float4 lf1 = *(const float4*)(leaf + tg * 16 + 4);
      float4 lf2 = *(const float4*)(leaf + tg * 16 + 8);
      float4 lf3 = *(const float4*)(leaf + tg * 16 + 12);
      float c2x = th.x * inv_tau, c2y = th.y * inv_tau,
            c2z = th.z * inv_tau, c2w = th.w * inv_tau;
      #pragma unroll
      for (int nf = 0; nf < 2; ++nf) {
        float p0 = __builtin_amdgcn_rcpf(1.0f + __expf(fmaf(acc[af][nf][g * 4 + 0], -inv_tau, c2x)));
        float p1 = __builtin_amdgcn_rcpf(1.0f + __expf(fmaf(acc[af][nf][g * 4 + 1], -inv_tau, c2y)));
        float p2 = __builtin_amdgcn_rcpf(1.0f + __expf(fmaf(acc[af][nf][g * 4 + 2], -inv_tau, c2z)));
        float p3 = __builtin_amdgcn_rcpf(1.0f + __expf(fmaf(acc[af][nf][g * 4 + 3], -inv_tau, c2w)));
        float q0 = 1.0f - p0, q1 = 1.0f - p1, q2 = 1.0f - p2, q3 = 1.0f - p3;
        float A0 = lf0.x * q0 + lf0.y * p0;
        float A1 = lf0.z * q0 + lf0.w * p0;
        float A2 = lf1.x * q0 + lf1.y * p0;
        float A3 = lf1.z * q0 + lf1.w * p0;
        float A4 = lf2.x * q0 + lf2.y * p0;
        float A5 = lf2.z * q0 + lf2.w * p0;
        float A6 = lf3.x * q0 + lf3.y * p0;
        float A7 = lf3.z * q0 + lf3.w * p0;
        float B0 = A0 * q1 + A1 * p1;
        float B1 = A2 * q1 + A3 * p1;
        float B2 = A4 * q1 + A5 * p1;
        float B3 = A6 * q1 + A7 * p1;
        float C0 = B0 * q2 + B1 * p2;
        float C1 = B2 * q2 + B3 * p2;
        float o  = C0 * q3 + C1 * p3;
        int bl = wn * 64 + nf * 32 + col;    // batch within block [0,128)
        eb[bl * 68 + tl] = o;
      }
    }
  }
  __syncthreads();

  // coalesced store: 128 batch rows x 64 trees, float4 per thread-slot
  #pragma unroll
  for (int pass = 0; pass < 8; ++pass) {
    int row = pass * 16 + (tid >> 4);
    int s   = tid & 15;
    float4 v = *(const float4*)(eb + row * 68 + s * 4);
    *(float4*)(out + (size_t)(n0 + row) * T_ + t0 + s * 4) = v;
  }
}

extern "C" void kernel_launch(void* const* d_in, const int* in_sizes, int n_in,
                              void* d_out, int out_size, void* d_ws, size_t ws_size,
                              hipStream_t stream) {
  const float* x    = (const float*)d_in[0];  // (B, F)
  const float* fl   = (const float*)d_in[1];  // (T, D, F)
  const float* thr  = (const float*)d_in[2];  // (T, D)
  const float* leaf = (const float*)d_in[3];  // (T, 16)
  float* out = (float*)d_out;                 // (B, T)

  unsigned short* wbF = (unsigned short*)d_ws;                                  // 8 MB
  unsigned short* xbF = (unsigned short*)((char*)d_ws + (size_t)KC_ * M_ * 16); // 4 MB

  prep<<<dim3(1024 + M_ / 4), dim3(256), 0, stream>>>(x, fl, xbF, wbF);
  odst_mfma<<<dim3(1024), dim3(256), 0, stream>>>(wbF, xbF, thr, leaf, out);
}